// Round 21
// baseline (289.729 us; speedup 1.0000x reference)
//
#include <hip/hip_runtime.h>

// Problem constants (BuNN layer)
#define CC   512      // channels
#define BB_  128      // bundles (4 channels each: [i=2][t=2])
#define BM 64
#define BN 128
#define BK 64

typedef __attribute__((ext_vector_type(8))) short short8;
typedef __attribute__((ext_vector_type(8))) unsigned short u16x8;
typedef __attribute__((ext_vector_type(4))) float f32x4;
typedef __attribute__((ext_vector_type(2))) float f32x2;
typedef __attribute__((ext_vector_type(4))) unsigned short u16x4;
typedef __attribute__((ext_vector_type(2))) unsigned short u16x2;

__device__ __forceinline__ unsigned short f2bf(float f) {
  union { float f; unsigned u; } v; v.f = f;
  return (unsigned short)((v.u + 0x7FFFu + ((v.u >> 16) & 1u)) >> 16);
}
__device__ __forceinline__ float bf2f(unsigned short b) {
  union { unsigned u; float f; } v; v.u = ((unsigned)b) << 16;
  return v.f;
}

// async global->LDS, 16B per lane; lds dest is wave-uniform base + lane*16
__device__ __forceinline__ void gload_lds16(const unsigned short* g, unsigned short* l) {
  __builtin_amdgcn_global_load_lds(
      (const __attribute__((address_space(1))) void*)g,
      (__attribute__((address_space(3))) void*)l, 16, 0, 0);
}

// ---------------- init: zero all accumulator scratch in ONE kernel ----------------
__global__ void k_zero(int* __restrict__ a, int* __restrict__ b, int* __restrict__ c,
                       float* __restrict__ d, float* __restrict__ e, int n) {
  int i = blockIdx.x * blockDim.x + threadIdx.x;
  if (i < n) { a[i] = 0; b[i] = 0; c[i] = 0; }
  if (i < CC) { d[i] = 0.f; e[i] = 0.f; }
}

// ---------------- graph prep ----------------
__global__ void k_count(const int* __restrict__ src, const int* __restrict__ dst,
                        int* __restrict__ cnt_src, int* __restrict__ cnt_dst, int E) {
  int e = blockIdx.x * blockDim.x + threadIdx.x;
  if (e < E) {
    atomicAdd(&cnt_src[src[e]], 1);
    atomicAdd(&cnt_dst[dst[e]], 1);
  }
}

// prefix sum of cnt_dst -> rp
__global__ __launch_bounds__(1024) void k_scan(const int* __restrict__ cnt,
                                               int* __restrict__ rp, int n) {
  __shared__ int sm[1024];
  int tid = threadIdx.x;
  int chunk = (n + 1023) >> 10;
  int beg = tid * chunk;
  int end = beg + chunk; if (end > n) end = n;
  int s = 0;
  for (int i = beg; i < end && i < n; ++i) s += cnt[i];
  sm[tid] = s;
  __syncthreads();
  for (int off = 1; off < 1024; off <<= 1) {
    int v = (tid >= off) ? sm[tid - off] : 0;
    __syncthreads();
    sm[tid] += v;
    __syncthreads();
  }
  int run = (tid == 0) ? 0 : sm[tid - 1];
  for (int i = beg; i < end && i < n; ++i) { rp[i] = run; run += cnt[i]; }
  if (tid == 0) rp[n] = sm[1023];
}

__global__ void k_fill(const int* __restrict__ src, const int* __restrict__ dst,
                       const int* __restrict__ rp, int* __restrict__ fil,
                       int* __restrict__ col, int E) {
  int e = blockIdx.x * blockDim.x + threadIdx.x;
  if (e < E) {
    int d = dst[e];
    int p = atomicAdd(&fil[d], 1);
    col[rp[d] + p] = src[e];
  }
}

// ---------------- converts ----------------
__global__ void k_conv_bf16(const float* __restrict__ in, unsigned short* __restrict__ out,
                            int validRows, int total4) {
  int i4 = blockIdx.x * blockDim.x + threadIdx.x;
  if (i4 >= total4) return;
  int row = i4 / (CC / 4);
  u16x4 o;
  if (row < validRows) {
    f32x4 v = ((const f32x4*)in)[i4];
    o[0] = f2bf(v[0]); o[1] = f2bf(v[1]); o[2] = f2bf(v[2]); o[3] = f2bf(v[3]);
  } else {
    o[0] = 0; o[1] = 0; o[2] = 0; o[3] = 0;
  }
  ((u16x4*)out)[i4] = o;
}

// All three weight transposes in one launch: z=0: W1[512][512], z=1: W2[512][128], z=2: Wlin
__global__ void k_transconv_all(const float* __restrict__ W1, const float* __restrict__ W2,
                                const float* __restrict__ Wlin,
                                unsigned short* __restrict__ W1t, unsigned short* __restrict__ W2t,
                                unsigned short* __restrict__ Wlt) {
  const float* W; unsigned short* Wt; int K, Nw;
  if (blockIdx.z == 0)      { W = W1;   Wt = W1t; K = 512; Nw = 512; }
  else if (blockIdx.z == 1) { W = W2;   Wt = W2t; K = 512; Nw = 128; if (blockIdx.x >= 4) return; }
  else                      { W = Wlin; Wt = Wlt; K = 512; Nw = 512; }
  __shared__ float tile[32][33];
  int n0 = blockIdx.x * 32, k0 = blockIdx.y * 32;
  int tx = threadIdx.x, ty = threadIdx.y;          // 32 x 8
  for (int j = 0; j < 4; ++j)
    tile[ty + j * 8][tx] = W[(k0 + ty + j * 8) * Nw + n0 + tx];
  __syncthreads();
  for (int j = 0; j < 4; ++j)
    Wt[(n0 + ty + j * 8) * K + k0 + tx] = f2bf(tile[tx][ty + j * 8]);
}

// ---------------- GEMM epilogue helper (EPI 0/1/2 scalar path) ----------------
template <int EPI>
__device__ __forceinline__ void epi_store(float v, int row, int colL, void* outp,
                                          const float* x, unsigned short* c0,
                                          int Nw, int nvalid) {
  if (EPI == 0) {
    ((float*)outp)[(size_t)row * Nw + colL] = v;
  } else if (EPI == 1) {
    float g = 0.5f * v * (1.0f + erff(v * 0.70710678118654752f));
    ((unsigned short*)outp)[(size_t)row * Nw + colL] = f2bf(g);
  } else {
    size_t bidx = (size_t)row * Nw + colL;     // (node, bundle)
    if (row < nvalid) {
      float sv, cv;
      sincosf(v, &sv, &cv);
      u16x2 o; o[0] = f2bf(cv); o[1] = f2bf(sv);
      ((u16x2*)outp)[bidx] = o;
      f32x4 xv = ((const f32x4*)x)[bidx];
      u16x4 rr;
      rr[0] = f2bf(cv * xv[0] - sv * xv[2]);
      rr[1] = f2bf(cv * xv[1] - sv * xv[3]);
      rr[2] = f2bf(sv * xv[0] + cv * xv[2]);
      rr[3] = f2bf(sv * xv[1] + cv * xv[3]);
      ((u16x4*)c0)[bidx] = rr;
    } else {
      u16x4 rr; rr[0] = 0; rr[1] = 0; rr[2] = 0; rr[3] = 0;
      ((u16x4*)c0)[bidx] = rr;
    }
  }
}

// ---------------- GEMM 64x128, BK=64 dbuf gload_lds + row-XOR swizzle + XCD grid ----------
// Round-20 post-mortem: GEMMs are per-K-step latency-exposure bound (16 barrier rounds).
// BK 32->64 halves the rounds (8) at the SAME occupancy (48KB LDS -> 3 blocks/CU = 37.5%,
// matching the measured 38-40%). Rows are now 128B: lane covers row l>>3, chunk l&7;
// swizzle chunk^=row&7 on the global source, read chunk=(s*4+kg)^(l15&7) -> 2 lanes/bank.
template <int EPI>
__global__ __launch_bounds__(256) void k_gemm(const unsigned short* __restrict__ A,
                                              const unsigned short* __restrict__ Bt,
                                              const float* __restrict__ bias,
                                              void* __restrict__ outp,
                                              const float* __restrict__ x,
                                              unsigned short* __restrict__ c0,
                                              const u16x2* __restrict__ csr,
                                              float* __restrict__ csum,
                                              float* __restrict__ csq,
                                              int K, int Nw, int nvalid, int ntn) {
  __shared__ unsigned short As[2][BM * BK];   // 2 x 8KB
  __shared__ unsigned short Bs[2][BN * BK];   // 2 x 16KB
  __shared__ float s_sum[BN], s_sq[BN];       // EPI3 stats
  // m204 bijective XCD swizzle: hardware d -> work w (XCD d%8 gets contiguous chunk)
  const int nwg = gridDim.x;
  const int d = blockIdx.x;
  const int xcd = d & 7, li = d >> 3;
  const int q = nwg >> 3, r = nwg & 7;
  const int w = (xcd < r ? xcd * (q + 1) : r * (q + 1) + (xcd - r) * q) + li;
  const int m0 = (w / ntn) * BM;
  const int n0 = (w % ntn) * BN;
  const int tid = threadIdx.x;
  const int wid = tid >> 6, lane = tid & 63;
  const int wr = wid >> 1, wc = wid & 1;            // wave -> 32x64 quadrant
  const int l15 = lane & 15, kg = lane >> 4;
  // staging: lane covers row l>>3 within an 8-row group, source chunk (l&7)^(l>>3)
  const int srow8 = lane >> 3;                      // 0..7
  const int schunk = ((lane & 7) ^ srow8) * 8;      // swizzled source elem offset
  // read-side: sub-step s chunk (s*4+kg) lives at LDS chunk (s*4+kg)^(row&7), row&7=l15&7
  const int rx = l15 & 7;

  if (EPI == 3 && tid < BN) { s_sum[tid] = 0.f; s_sq[tid] = 0.f; }

  f32x4 acc00 = {}, acc01 = {}, acc02 = {}, acc03 = {};
  f32x4 acc10 = {}, acc11 = {}, acc12 = {}, acc13 = {};

  const int nt = K / BK;                            // 8
#define STAGE(BUF, KT)                                                              \
  do {                                                                              \
    gload_lds16(&A[(size_t)(m0 + wid * 16 + 0 + srow8) * K + (KT) + schunk],        \
                &As[BUF][wid * 1024]);                                              \
    gload_lds16(&A[(size_t)(m0 + wid * 16 + 8 + srow8) * K + (KT) + schunk],        \
                &As[BUF][wid * 1024 + 512]);                                        \
    gload_lds16(&Bt[(size_t)(n0 + wid * 32 +  0 + srow8) * K + (KT) + schunk],      \
                &Bs[BUF][wid * 2048]);                                              \
    gload_lds16(&Bt[(size_t)(n0 + wid * 32 +  8 + srow8) * K + (KT) + schunk],      \
                &Bs[BUF][wid * 2048 + 512]);                                        \
    gload_lds16(&Bt[(size_t)(n0 + wid * 32 + 16 + srow8) * K + (KT) + schunk],      \
                &Bs[BUF][wid * 2048 + 1024]);                                       \
    gload_lds16(&Bt[(size_t)(n0 + wid * 32 + 24 + srow8) * K + (KT) + schunk],      \
                &Bs[BUF][wid * 2048 + 1536]);                                       \
  } while (0)

  STAGE(0, 0);
  __syncthreads();

  for (int kk = 0; kk < nt; ++kk) {
    const int cur = kk & 1;
    if (kk + 1 < nt) STAGE(cur ^ 1, (kk + 1) * BK);
    #pragma unroll
    for (int s = 0; s < 2; ++s) {
      const int ck = ((s * 4 + kg) ^ rx) * 8;
      short8 af0 = *(const short8*)&As[cur][(wr * 32 +  0 + l15) * BK + ck];
      short8 af1 = *(const short8*)&As[cur][(wr * 32 + 16 + l15) * BK + ck];
      short8 bg0 = *(const short8*)&Bs[cur][(wc * 64 +  0 + l15) * BK + ck];
      short8 bg1 = *(const short8*)&Bs[cur][(wc * 64 + 16 + l15) * BK + ck];
      short8 bg2 = *(const short8*)&Bs[cur][(wc * 64 + 32 + l15) * BK + ck];
      short8 bg3 = *(const short8*)&Bs[cur][(wc * 64 + 48 + l15) * BK + ck];
      acc00 = __builtin_amdgcn_mfma_f32_16x16x32_bf16(af0, bg0, acc00, 0, 0, 0);
      acc01 = __builtin_amdgcn_mfma_f32_16x16x32_bf16(af0, bg1, acc01, 0, 0, 0);
      acc02 = __builtin_amdgcn_mfma_f32_16x16x32_bf16(af0, bg2, acc02, 0, 0, 0);
      acc03 = __builtin_amdgcn_mfma_f32_16x16x32_bf16(af0, bg3, acc03, 0, 0, 0);
      acc10 = __builtin_amdgcn_mfma_f32_16x16x32_bf16(af1, bg0, acc10, 0, 0, 0);
      acc11 = __builtin_amdgcn_mfma_f32_16x16x32_bf16(af1, bg1, acc11, 0, 0, 0);
      acc12 = __builtin_amdgcn_mfma_f32_16x16x32_bf16(af1, bg2, acc12, 0, 0, 0);
      acc13 = __builtin_amdgcn_mfma_f32_16x16x32_bf16(af1, bg3, acc13, 0, 0, 0);
    }
    __syncthreads();
  }
#undef STAGE

  if (EPI != 3) {
#define DO_EPI(ACC, MI, NI)                                                     \
  do {                                                                          \
    const int row_ = m0 + wr * 32 + (MI) * 16 + kg * 4;                         \
    const int col_ = n0 + wc * 64 + (NI) * 16 + l15;                            \
    const float b_ = bias[col_];                                                \
    epi_store<EPI>(ACC[0] + b_, row_ + 0, col_, outp, x, c0, Nw, nvalid);       \
    epi_store<EPI>(ACC[1] + b_, row_ + 1, col_, outp, x, c0, Nw, nvalid);       \
    epi_store<EPI>(ACC[2] + b_, row_ + 2, col_, outp, x, c0, Nw, nvalid);       \
    epi_store<EPI>(ACC[3] + b_, row_ + 3, col_, outp, x, c0, Nw, nvalid);       \
  } while (0)

    DO_EPI(acc00, 0, 0); DO_EPI(acc01, 0, 1); DO_EPI(acc02, 0, 2); DO_EPI(acc03, 0, 3);
    DO_EPI(acc10, 1, 0); DO_EPI(acc11, 1, 1); DO_EPI(acc12, 1, 2); DO_EPI(acc13, 1, 3);
#undef DO_EPI
  } else {
    // fused: h2 pair (c, c+2) lives in lanes (l, l^2); out_pre(bf16) = x + R^T h2; BN stats
    float pS0 = 0.f, pS1 = 0.f, pS2 = 0.f, pS3 = 0.f;
    float pQ0 = 0.f, pQ1 = 0.f, pQ2 = 0.f, pQ3 = 0.f;
    const int bi = (l15 >> 1) & 1;                 // i index within bundle
#define DO_EPI3(ACC, MI, NI, PS, PQ)                                            \
  do {                                                                          \
    const int row_ = m0 + wr * 32 + (MI) * 16 + kg * 4;                         \
    const int col_ = n0 + wc * 64 + (NI) * 16 + l15;                            \
    const float b_ = bias[col_];                                                \
    _Pragma("unroll")                                                           \
    for (int r2 = 0; r2 < 4; ++r2) {                                            \
      float v = ACC[r2] + b_;                                                   \
      float vp = __shfl_xor(v, 2);   /* partner includes its own bias */        \
      int rr_ = row_ + r2;                                                      \
      if (rr_ < nvalid) {                                                       \
        u16x2 ac = csr[(size_t)rr_ * BB_ + (col_ >> 2)];                        \
        float c_ = bf2f(ac[0]), s_ = bf2f(ac[1]);                               \
        float ov = bi == 0 ? c_ * v + s_ * vp : c_ * v - s_ * vp;               \
        ov += x[(size_t)rr_ * CC + col_];                                       \
        ((unsigned short*)outp)[(size_t)rr_ * CC + col_] = f2bf(ov);            \
        PS += ov; PQ += ov * ov;                                                \
      }                                                                         \
    }                                                                           \
  } while (0)

    DO_EPI3(acc00, 0, 0, pS0, pQ0); DO_EPI3(acc01, 0, 1, pS1, pQ1);
    DO_EPI3(acc02, 0, 2, pS2, pQ2); DO_EPI3(acc03, 0, 3, pS3, pQ3);
    DO_EPI3(acc10, 1, 0, pS0, pQ0); DO_EPI3(acc11, 1, 1, pS1, pQ1);
    DO_EPI3(acc12, 1, 2, pS2, pQ2); DO_EPI3(acc13, 1, 3, pS3, pQ3);
#undef DO_EPI3
    const int cb = wc * 64 + l15;                  // col within block, + NI*16
    atomicAdd(&s_sum[cb +  0], pS0); atomicAdd(&s_sq[cb +  0], pQ0);
    atomicAdd(&s_sum[cb + 16], pS1); atomicAdd(&s_sq[cb + 16], pQ1);
    atomicAdd(&s_sum[cb + 32], pS2); atomicAdd(&s_sq[cb + 32], pQ2);
    atomicAdd(&s_sum[cb + 48], pS3); atomicAdd(&s_sq[cb + 48], pQ3);
    __syncthreads();
    if (tid < BN) {
      atomicAdd(&csum[n0 + tid], s_sum[tid]);
      atomicAdd(&csq[n0 + tid], s_sq[tid]);
    }
  }
}

// ---------------- diffusion (bf16): nxt = coef*(cur - (1/cnt)*sum_in(cur)) ----------------
__global__ __launch_bounds__(256) void k_diffuse(const unsigned short* __restrict__ cur,
                                                 unsigned short* __restrict__ nxt,
                                                 const int* __restrict__ cnt_src,
                                                 const int* __restrict__ rp,
                                                 const int* __restrict__ col,
                                                 float coef, int n) {
  int w = threadIdx.x >> 6, lane = threadIdx.x & 63;
  int v = blockIdx.x * 4 + w;
  if (v >= n) return;
  int beg = rp[v], end = rp[v + 1];
  const u16x8* curv = (const u16x8*)cur;
  float s[8] = {0.f,0.f,0.f,0.f,0.f,0.f,0.f,0.f};
  #pragma unroll 4
  for (int e = beg; e < end; ++e) {
    int u = col[e];
    u16x8 r = curv[(size_t)u * 64 + lane];
    #pragma unroll
    for (int j = 0; j < 8; ++j) s[j] += bf2f(r[j]);
  }
  float di = 1.0f / (float)cnt_src[v];
  u16x8 cv = curv[(size_t)v * 64 + lane];
  u16x8 o;
  #pragma unroll
  for (int j = 0; j < 8; ++j) o[j] = f2bf((bf2f(cv[j]) - s[j] * di) * coef);
  ((u16x8*)nxt)[(size_t)v * 64 + lane] = o;
}

// ---------------- last diffusion step fused with h-sum ----------------
__global__ __launch_bounds__(256) void k_diffuse_final(const unsigned short* __restrict__ c0,
                                                       const unsigned short* __restrict__ c1,
                                                       const unsigned short* __restrict__ c2,
                                                       const unsigned short* __restrict__ cur,
                                                       unsigned short* __restrict__ hb,
                                                       const int* __restrict__ cnt_src,
                                                       const int* __restrict__ rp,
                                                       const int* __restrict__ col,
                                                       float coef, int n) {
  int w = threadIdx.x >> 6, lane = threadIdx.x & 63;
  int v = blockIdx.x * 4 + w;
  if (v >= n) return;
  int beg = rp[v], end = rp[v + 1];
  const u16x8* curv = (const u16x8*)cur;
  float s[8] = {0.f,0.f,0.f,0.f,0.f,0.f,0.f,0.f};
  #pragma unroll 4
  for (int e = beg; e < end; ++e) {
    int u = col[e];
    u16x8 r = curv[(size_t)u * 64 + lane];
    #pragma unroll
    for (int j = 0; j < 8; ++j) s[j] += bf2f(r[j]);
  }
  float di = 1.0f / (float)cnt_src[v];
  size_t o = (size_t)v * 64 + lane;
  u16x8 cv = curv[o];
  u16x8 a0 = ((const u16x8*)c0)[o];
  u16x8 a1 = ((const u16x8*)c1)[o];
  u16x8 a2 = ((const u16x8*)c2)[o];
  u16x8 hv;
  #pragma unroll
  for (int j = 0; j < 8; ++j) {
    float c3v = bf2f(cv[j]);
    float c4v = (c3v - s[j] * di) * coef;
    hv[j] = f2bf(bf2f(a0[j]) + bf2f(a1[j]) + bf2f(a2[j]) + c3v + c4v);
  }
  ((u16x8*)hb)[o] = hv;
}

// ---------------- BN finalize + normalize: bf16 out_pre -> f32 d_out ----------------
__global__ __launch_bounds__(256) void k_norm(const unsigned short* __restrict__ outpre,
                                              float* __restrict__ out,
                                              const float* __restrict__ colsum,
                                              const float* __restrict__ colsq,
                                              const float* __restrict__ gamma,
                                              const float* __restrict__ beta,
                                              float invn, int n4) {
  __shared__ float ssc[CC], ssh[CC];
  int t = threadIdx.x;
  for (int c = t; c < CC; c += 256) {
    float mean = colsum[c] * invn;
    float var = colsq[c] * invn - mean * mean;
    float sc = gamma[c] * rsqrtf(var + 1e-5f);
    ssc[c] = sc;
    ssh[c] = beta[c] - mean * sc;
  }
  __syncthreads();
  int i = blockIdx.x * blockDim.x + t;
  if (i >= n4) return;
  int c4 = i & (CC / 4 - 1);
  u16x4 v = ((const u16x4*)outpre)[i];
  f32x4 sc = *(const f32x4*)&ssc[c4 * 4];
  f32x4 sh = *(const f32x4*)&ssh[c4 * 4];
  f32x4 o;
  o[0] = bf2f(v[0]) * sc[0] + sh[0];
  o[1] = bf2f(v[1]) * sc[1] + sh[1];
  o[2] = bf2f(v[2]) * sc[2] + sh[2];
  o[3] = bf2f(v[3]) * sc[3] + sh[3];
  ((f32x4*)out)[i] = o;
}

// ---------------- orchestration ----------------
extern "C" void kernel_launch(void* const* d_in, const int* in_sizes, int n_in,
                              void* d_out, int out_size, void* d_ws, size_t ws_size,
                              hipStream_t stream) {
  (void)n_in; (void)out_size; (void)ws_size;
  const float* x    = (const float*)d_in[0];
  const float* W1   = (const float*)d_in[1];
  const float* b1   = (const float*)d_in[2];
  const float* W2   = (const float*)d_in[3];
  const float* b2   = (const float*)d_in[4];
  const float* Wlin = (const float*)d_in[5];
  const float* blin = (const float*)d_in[6];
  const float* gamma = (const float*)d_in[7];
  const float* beta  = (const float*)d_in[8];
  const int*   ei    = (const int*)d_in[9];

  const int n   = in_sizes[0] / CC;          // 20000
  const int E   = in_sizes[9] / 2;           // 160000
  const int GNN = in_sizes[2];               // 512
  const int NBP = in_sizes[4];               // 128
  const int* src = ei;
  const int* dst = ei + E;
  const int mt64 = (n + BM - 1) / BM;        // 313
  const int mpad = 20096;                    // multiple of 64 and 128
  const size_t SB = (size_t)mpad * CC;       // elements per bf16 buffer

  char* ws = (char*)d_ws;
  size_t off = 0;
  auto alloc = [&](size_t bytes) -> void* {
    void* p = ws + off;
    off = (off + bytes + 255) & ~(size_t)255;
    return p;
  };
  int*   cnt_src = (int*)alloc((size_t)n * 4);
  int*   cnt_dst = (int*)alloc((size_t)n * 4);
  int*   fil     = (int*)alloc((size_t)n * 4);
  int*   rp      = (int*)alloc((size_t)(n + 1) * 4);
  int*   colx    = (int*)alloc((size_t)E * 4);
  float* colsum  = (float*)alloc(CC * 4);
  float* colsq   = (float*)alloc(CC * 4);
  unsigned short* W1t = (unsigned short*)alloc((size_t)GNN * CC * 2);
  unsigned short* W2t = (unsigned short*)alloc((size_t)NBP * GNN * 2);
  unsigned short* Wlt = (unsigned short*)alloc((size_t)CC * CC * 2);
  u16x2* cs = (u16x2*)alloc((size_t)mpad * BB_ * 4);       // bf16 (cos,sin)
  unsigned short* c0 = (unsigned short*)alloc(SB * 2);     // phase A: xb; later out_pre
  unsigned short* c1 = (unsigned short*)alloc(SB * 2);     // phase A: G
  unsigned short* c2 = (unsigned short*)alloc(SB * 2);
  unsigned short* c3 = (unsigned short*)alloc(SB * 2);
  unsigned short* hb = (unsigned short*)alloc(SB * 2);
  unsigned short* xb = c0;
  unsigned short* G  = c1;
  unsigned short* outpre = c0;               // bf16 out staging (c0 dead after diffuse_final)

  // zero accumulator scratch
  k_zero<<<(n + 255) / 256, 256, 0, stream>>>(cnt_src, cnt_dst, fil, colsum, colsq, n);

  // graph prep
  k_count<<<(E + 255) / 256, 256, 0, stream>>>(src, dst, cnt_src, cnt_dst, E);
  k_scan<<<1, 1024, 0, stream>>>(cnt_dst, rp, n);
  k_fill<<<(E + 255) / 256, 256, 0, stream>>>(src, dst, rp, fil, colx, E);

  // converts
  int total4 = mpad * (CC / 4);
  k_conv_bf16<<<(total4 + 255) / 256, 256, 0, stream>>>(x, xb, n, total4);
  k_transconv_all<<<dim3(16, 16, 3), dim3(32, 8), 0, stream>>>(W1, W2, Wlin, W1t, W2t, Wlt);

  // struct encoder: G = gelu(x@W1+b1); GEMM2 fused: cs=bf16(cos,sin)(G@W2+b2), c0=bf16(Rx)
  k_gemm<1><<<mt64 * (GNN / BN), 256, 0, stream>>>(xb, W1t, b1, (void*)G, nullptr, nullptr,
                                                   nullptr, nullptr, nullptr, CC, GNN, n, GNN / BN);
  k_gemm<2><<<mt64 * (NBP / BN), 256, 0, stream>>>(G, W2t, b2, (void*)cs, x, c0,
                                                   nullptr, nullptr, nullptr, GNN, NBP, n, NBP / BN);

  // diffusion: c0 -> c1 -> c2 -> c3; last step fused with h-sum -> hb
  k_diffuse<<<(n + 3) / 4, 256, 0, stream>>>(c0, c1, cnt_src, rp, colx, -1.0f, n);
  k_diffuse<<<(n + 3) / 4, 256, 0, stream>>>(c1, c2, cnt_src, rp, colx, -0.5f, n);
  k_diffuse<<<(n + 3) / 4, 256, 0, stream>>>(c2, c3, cnt_src, rp, colx, -(1.0f / 3.0f), n);
  k_diffuse_final<<<(n + 3) / 4, 256, 0, stream>>>(c0, c1, c2, c3, hb, cnt_src, rp, colx, -0.25f, n);

  // GEMM3 fused: out_pre(bf16) = x + R^T(hb@Wlin+blin) + BN column stats (out_pre = c0, dead)
  k_gemm<3><<<mt64 * (CC / BN), 256, 0, stream>>>(hb, Wlt, blin, (void*)outpre, x, nullptr,
                                                  cs, colsum, colsq, CC, CC, n, CC / BN);

  // BN finalize + normalize: bf16 out_pre -> f32 d_out
  int nb = n * BB_;
  k_norm<<<(nb + 255) / 256, 256, 0, stream>>>(outpre, (float*)d_out, colsum, colsq, gamma, beta,
                                               1.0f / (float)n, nb);
}

// Round 22
// 279.225 us; speedup vs baseline: 1.0376x; 1.0376x over previous
//
#include <hip/hip_runtime.h>

// Problem constants (BuNN layer)
#define CC   512      // channels
#define BB_  128      // bundles (4 channels each: [i=2][t=2])
#define BM 64
#define BN 128
#define BK 32

typedef __attribute__((ext_vector_type(8))) short short8;
typedef __attribute__((ext_vector_type(8))) unsigned short u16x8;
typedef __attribute__((ext_vector_type(4))) float f32x4;
typedef __attribute__((ext_vector_type(2))) float f32x2;
typedef __attribute__((ext_vector_type(4))) unsigned short u16x4;
typedef __attribute__((ext_vector_type(2))) unsigned short u16x2;

__device__ __forceinline__ unsigned short f2bf(float f) {
  union { float f; unsigned u; } v; v.f = f;
  return (unsigned short)((v.u + 0x7FFFu + ((v.u >> 16) & 1u)) >> 16);
}
__device__ __forceinline__ float bf2f(unsigned short b) {
  union { unsigned u; float f; } v; v.u = ((unsigned)b) << 16;
  return v.f;
}

// async global->LDS, 16B per lane; lds dest is wave-uniform base + lane*16
__device__ __forceinline__ void gload_lds16(const unsigned short* g, unsigned short* l) {
  __builtin_amdgcn_global_load_lds(
      (const __attribute__((address_space(1))) void*)g,
      (__attribute__((address_space(3))) void*)l, 16, 0, 0);
}

// ---------------- init: zero all accumulator scratch in ONE kernel ----------------
__global__ void k_zero(int* __restrict__ a, int* __restrict__ b, int* __restrict__ c,
                       float* __restrict__ d, float* __restrict__ e, int n) {
  int i = blockIdx.x * blockDim.x + threadIdx.x;
  if (i < n) { a[i] = 0; b[i] = 0; c[i] = 0; }
  if (i < CC) { d[i] = 0.f; e[i] = 0.f; }
}

// ---------------- graph prep ----------------
__global__ void k_count(const int* __restrict__ src, const int* __restrict__ dst,
                        int* __restrict__ cnt_src, int* __restrict__ cnt_dst, int E) {
  int e = blockIdx.x * blockDim.x + threadIdx.x;
  if (e < E) {
    atomicAdd(&cnt_src[src[e]], 1);
    atomicAdd(&cnt_dst[dst[e]], 1);
  }
}

// prefix sum of cnt_dst -> rp
__global__ __launch_bounds__(1024) void k_scan(const int* __restrict__ cnt,
                                               int* __restrict__ rp, int n) {
  __shared__ int sm[1024];
  int tid = threadIdx.x;
  int chunk = (n + 1023) >> 10;
  int beg = tid * chunk;
  int end = beg + chunk; if (end > n) end = n;
  int s = 0;
  for (int i = beg; i < end && i < n; ++i) s += cnt[i];
  sm[tid] = s;
  __syncthreads();
  for (int off = 1; off < 1024; off <<= 1) {
    int v = (tid >= off) ? sm[tid - off] : 0;
    __syncthreads();
    sm[tid] += v;
    __syncthreads();
  }
  int run = (tid == 0) ? 0 : sm[tid - 1];
  for (int i = beg; i < end && i < n; ++i) { rp[i] = run; run += cnt[i]; }
  if (tid == 0) rp[n] = sm[1023];
}

__global__ void k_fill(const int* __restrict__ src, const int* __restrict__ dst,
                       const int* __restrict__ rp, int* __restrict__ fil,
                       int* __restrict__ col, int E) {
  int e = blockIdx.x * blockDim.x + threadIdx.x;
  if (e < E) {
    int d = dst[e];
    int p = atomicAdd(&fil[d], 1);
    col[rp[d] + p] = src[e];
  }
}

// ---------------- converts ----------------
__global__ void k_conv_bf16(const float* __restrict__ in, unsigned short* __restrict__ out,
                            int validRows, int total4) {
  int i4 = blockIdx.x * blockDim.x + threadIdx.x;
  if (i4 >= total4) return;
  int row = i4 / (CC / 4);
  u16x4 o;
  if (row < validRows) {
    f32x4 v = ((const f32x4*)in)[i4];
    o[0] = f2bf(v[0]); o[1] = f2bf(v[1]); o[2] = f2bf(v[2]); o[3] = f2bf(v[3]);
  } else {
    o[0] = 0; o[1] = 0; o[2] = 0; o[3] = 0;
  }
  ((u16x4*)out)[i4] = o;
}

// All three weight transposes in one launch: z=0: W1[512][512], z=1: W2[512][128], z=2: Wlin
__global__ void k_transconv_all(const float* __restrict__ W1, const float* __restrict__ W2,
                                const float* __restrict__ Wlin,
                                unsigned short* __restrict__ W1t, unsigned short* __restrict__ W2t,
                                unsigned short* __restrict__ Wlt) {
  const float* W; unsigned short* Wt; int K, Nw;
  if (blockIdx.z == 0)      { W = W1;   Wt = W1t; K = 512; Nw = 512; }
  else if (blockIdx.z == 1) { W = W2;   Wt = W2t; K = 512; Nw = 128; if (blockIdx.x >= 4) return; }
  else                      { W = Wlin; Wt = Wlt; K = 512; Nw = 512; }
  __shared__ float tile[32][33];
  int n0 = blockIdx.x * 32, k0 = blockIdx.y * 32;
  int tx = threadIdx.x, ty = threadIdx.y;          // 32 x 8
  for (int j = 0; j < 4; ++j)
    tile[ty + j * 8][tx] = W[(k0 + ty + j * 8) * Nw + n0 + tx];
  __syncthreads();
  for (int j = 0; j < 4; ++j)
    Wt[(n0 + ty + j * 8) * K + k0 + tx] = f2bf(tile[tx][ty + j * 8]);
}

// ---------------- GEMM epilogue helper (EPI 0/1/2 scalar path) ----------------
// EPI 2 stores cs as bf16 pair (u16x2) — halves cs traffic both ways.
template <int EPI>
__device__ __forceinline__ void epi_store(float v, int row, int colL, void* outp,
                                          const float* x, unsigned short* c0,
                                          int Nw, int nvalid) {
  if (EPI == 0) {
    ((float*)outp)[(size_t)row * Nw + colL] = v;
  } else if (EPI == 1) {
    float g = 0.5f * v * (1.0f + erff(v * 0.70710678118654752f));
    ((unsigned short*)outp)[(size_t)row * Nw + colL] = f2bf(g);
  } else {
    size_t bidx = (size_t)row * Nw + colL;     // (node, bundle)
    if (row < nvalid) {
      float sv, cv;
      sincosf(v, &sv, &cv);
      u16x2 o; o[0] = f2bf(cv); o[1] = f2bf(sv);
      ((u16x2*)outp)[bidx] = o;
      f32x4 xv = ((const f32x4*)x)[bidx];
      u16x4 rr;
      rr[0] = f2bf(cv * xv[0] - sv * xv[2]);
      rr[1] = f2bf(cv * xv[1] - sv * xv[3]);
      rr[2] = f2bf(sv * xv[0] + cv * xv[2]);
      rr[3] = f2bf(sv * xv[1] + cv * xv[3]);
      ((u16x4*)c0)[bidx] = rr;
    } else {
      u16x4 rr; rr[0] = 0; rr[1] = 0; rr[2] = 0; rr[3] = 0;
      ((u16x4*)c0)[bidx] = rr;
    }
  }
}

// ---------------- GEMM 64x128, dbuf gload_lds + chunk-XOR swizzle + XCD-CHUNKED GRID ------
// (round-20 configuration — best measured: 279.3 us total)
// EPI 3: fused rotback+residual+BN-stats; cs read as bf16 pair; output written as bf16
// into a staging buffer (k_norm produces the final f32). Stats stay f32 (pre-quantization).
template <int EPI>
__global__ __launch_bounds__(256) void k_gemm(const unsigned short* __restrict__ A,
                                              const unsigned short* __restrict__ Bt,
                                              const float* __restrict__ bias,
                                              void* __restrict__ outp,
                                              const float* __restrict__ x,
                                              unsigned short* __restrict__ c0,
                                              const u16x2* __restrict__ csr,
                                              float* __restrict__ csum,
                                              float* __restrict__ csq,
                                              int K, int Nw, int nvalid, int ntn) {
  __shared__ unsigned short As[2][BM * BK];   // 2 x 4KB
  __shared__ unsigned short Bs[2][BN * BK];   // 2 x 8KB
  __shared__ float s_sum[BN], s_sq[BN];       // EPI3 stats
  // m204 bijective XCD swizzle: hardware d -> work w (XCD d%8 gets contiguous chunk)
  const int nwg = gridDim.x;
  const int d = blockIdx.x;
  const int xcd = d & 7, li = d >> 3;
  const int q = nwg >> 3, r = nwg & 7;
  const int w = (xcd < r ? xcd * (q + 1) : r * (q + 1) + (xcd - r) * q) + li;
  const int m0 = (w / ntn) * BM;
  const int n0 = (w % ntn) * BN;
  const int tid = threadIdx.x;
  const int wid = tid >> 6, lane = tid & 63;
  const int wr = wid >> 1, wc = wid & 1;            // wave -> 32x64 quadrant
  const int l15 = lane & 15, kg = lane >> 4;
  const int arow = wid * 16 + (lane >> 2);          // 0..63 (LDS row this lane stages)
  const int aseg = (((lane & 3) ^ ((arow >> 1) & 3)) * 8);   // pre-swizzled src chunk
  const int kgx = (kg ^ ((l15 >> 1) & 3)) * 8;               // matching read-side XOR

  if (EPI == 3 && tid < BN) { s_sum[tid] = 0.f; s_sq[tid] = 0.f; }

  f32x4 acc00 = {}, acc01 = {}, acc02 = {}, acc03 = {};
  f32x4 acc10 = {}, acc11 = {}, acc12 = {}, acc13 = {};

  const int nt = K / BK;
  gload_lds16(&A[(size_t)(m0 + arow) * K + aseg],       &As[0][wid * 512]);
  gload_lds16(&Bt[(size_t)(n0 + arow) * K + aseg],      &Bs[0][wid * 512]);
  gload_lds16(&Bt[(size_t)(n0 + 64 + arow) * K + aseg], &Bs[0][2048 + wid * 512]);
  __syncthreads();

  for (int kk = 0; kk < nt; ++kk) {
    const int cur = kk & 1;
    if (kk + 1 < nt) {
      const int kt = (kk + 1) * BK;
      gload_lds16(&A[(size_t)(m0 + arow) * K + kt + aseg],       &As[cur ^ 1][wid * 512]);
      gload_lds16(&Bt[(size_t)(n0 + arow) * K + kt + aseg],      &Bs[cur ^ 1][wid * 512]);
      gload_lds16(&Bt[(size_t)(n0 + 64 + arow) * K + kt + aseg], &Bs[cur ^ 1][2048 + wid * 512]);
    }
    short8 af0 = *(const short8*)&As[cur][(wr * 32 +  0 + l15) * BK + kgx];
    short8 af1 = *(const short8*)&As[cur][(wr * 32 + 16 + l15) * BK + kgx];
    short8 bg0 = *(const short8*)&Bs[cur][(wc * 64 +  0 + l15) * BK + kgx];
    short8 bg1 = *(const short8*)&Bs[cur][(wc * 64 + 16 + l15) * BK + kgx];
    short8 bg2 = *(const short8*)&Bs[cur][(wc * 64 + 32 + l15) * BK + kgx];
    short8 bg3 = *(const short8*)&Bs[cur][(wc * 64 + 48 + l15) * BK + kgx];
    acc00 = __builtin_amdgcn_mfma_f32_16x16x32_bf16(af0, bg0, acc00, 0, 0, 0);
    acc01 = __builtin_amdgcn_mfma_f32_16x16x32_bf16(af0, bg1, acc01, 0, 0, 0);
    acc02 = __builtin_amdgcn_mfma_f32_16x16x32_bf16(af0, bg2, acc02, 0, 0, 0);
    acc03 = __builtin_amdgcn_mfma_f32_16x16x32_bf16(af0, bg3, acc03, 0, 0, 0);
    acc10 = __builtin_amdgcn_mfma_f32_16x16x32_bf16(af1, bg0, acc10, 0, 0, 0);
    acc11 = __builtin_amdgcn_mfma_f32_16x16x32_bf16(af1, bg1, acc11, 0, 0, 0);
    acc12 = __builtin_amdgcn_mfma_f32_16x16x32_bf16(af1, bg2, acc12, 0, 0, 0);
    acc13 = __builtin_amdgcn_mfma_f32_16x16x32_bf16(af1, bg3, acc13, 0, 0, 0);
    __syncthreads();
  }

  if (EPI != 3) {
#define DO_EPI(ACC, MI, NI)                                                     \
  do {                                                                          \
    const int row_ = m0 + wr * 32 + (MI) * 16 + kg * 4;                         \
    const int col_ = n0 + wc * 64 + (NI) * 16 + l15;                            \
    const float b_ = bias[col_];                                                \
    epi_store<EPI>(ACC[0] + b_, row_ + 0, col_, outp, x, c0, Nw, nvalid);       \
    epi_store<EPI>(ACC[1] + b_, row_ + 1, col_, outp, x, c0, Nw, nvalid);       \
    epi_store<EPI>(ACC[2] + b_, row_ + 2, col_, outp, x, c0, Nw, nvalid);       \
    epi_store<EPI>(ACC[3] + b_, row_ + 3, col_, outp, x, c0, Nw, nvalid);       \
  } while (0)

    DO_EPI(acc00, 0, 0); DO_EPI(acc01, 0, 1); DO_EPI(acc02, 0, 2); DO_EPI(acc03, 0, 3);
    DO_EPI(acc10, 1, 0); DO_EPI(acc11, 1, 1); DO_EPI(acc12, 1, 2); DO_EPI(acc13, 1, 3);
#undef DO_EPI
  } else {
    // fused: h2 pair (c, c+2) lives in lanes (l, l^2); out_pre(bf16) = x + R^T h2; BN stats
    float pS0 = 0.f, pS1 = 0.f, pS2 = 0.f, pS3 = 0.f;
    float pQ0 = 0.f, pQ1 = 0.f, pQ2 = 0.f, pQ3 = 0.f;
    const int bi = (l15 >> 1) & 1;                 // i index within bundle
#define DO_EPI3(ACC, MI, NI, PS, PQ)                                            \
  do {                                                                          \
    const int row_ = m0 + wr * 32 + (MI) * 16 + kg * 4;                         \
    const int col_ = n0 + wc * 64 + (NI) * 16 + l15;                            \
    const float b_ = bias[col_];                                                \
    _Pragma("unroll")                                                           \
    for (int r2 = 0; r2 < 4; ++r2) {                                            \
      float v = ACC[r2] + b_;                                                   \
      float vp = __shfl_xor(v, 2);   /* partner includes its own bias */        \
      int rr_ = row_ + r2;                                                      \
      if (rr_ < nvalid) {                                                       \
        u16x2 ac = csr[(size_t)rr_ * BB_ + (col_ >> 2)];                        \
        float c_ = bf2f(ac[0]), s_ = bf2f(ac[1]);                               \
        float ov = bi == 0 ? c_ * v + s_ * vp : c_ * v - s_ * vp;               \
        ov += x[(size_t)rr_ * CC + col_];                                       \
        ((unsigned short*)outp)[(size_t)rr_ * CC + col_] = f2bf(ov);            \
        PS += ov; PQ += ov * ov;                                                \
      }                                                                         \
    }                                                                           \
  } while (0)

    DO_EPI3(acc00, 0, 0, pS0, pQ0); DO_EPI3(acc01, 0, 1, pS1, pQ1);
    DO_EPI3(acc02, 0, 2, pS2, pQ2); DO_EPI3(acc03, 0, 3, pS3, pQ3);
    DO_EPI3(acc10, 1, 0, pS0, pQ0); DO_EPI3(acc11, 1, 1, pS1, pQ1);
    DO_EPI3(acc12, 1, 2, pS2, pQ2); DO_EPI3(acc13, 1, 3, pS3, pQ3);
#undef DO_EPI3
    const int cb = wc * 64 + l15;                  // col within block, + NI*16
    atomicAdd(&s_sum[cb +  0], pS0); atomicAdd(&s_sq[cb +  0], pQ0);
    atomicAdd(&s_sum[cb + 16], pS1); atomicAdd(&s_sq[cb + 16], pQ1);
    atomicAdd(&s_sum[cb + 32], pS2); atomicAdd(&s_sq[cb + 32], pQ2);
    atomicAdd(&s_sum[cb + 48], pS3); atomicAdd(&s_sq[cb + 48], pQ3);
    __syncthreads();
    if (tid < BN) {
      atomicAdd(&csum[n0 + tid], s_sum[tid]);
      atomicAdd(&csq[n0 + tid], s_sq[tid]);
    }
  }
}

// ---------------- diffusion (bf16): nxt = coef*(cur - (1/cnt)*sum_in(cur)) ----------------
__global__ __launch_bounds__(256) void k_diffuse(const unsigned short* __restrict__ cur,
                                                 unsigned short* __restrict__ nxt,
                                                 const int* __restrict__ cnt_src,
                                                 const int* __restrict__ rp,
                                                 const int* __restrict__ col,
                                                 float coef, int n) {
  int w = threadIdx.x >> 6, lane = threadIdx.x & 63;
  int v = blockIdx.x * 4 + w;
  if (v >= n) return;
  int beg = rp[v], end = rp[v + 1];
  const u16x8* curv = (const u16x8*)cur;
  float s[8] = {0.f,0.f,0.f,0.f,0.f,0.f,0.f,0.f};
  #pragma unroll 4
  for (int e = beg; e < end; ++e) {
    int u = col[e];
    u16x8 r = curv[(size_t)u * 64 + lane];
    #pragma unroll
    for (int j = 0; j < 8; ++j) s[j] += bf2f(r[j]);
  }
  float di = 1.0f / (float)cnt_src[v];
  u16x8 cv = curv[(size_t)v * 64 + lane];
  u16x8 o;
  #pragma unroll
  for (int j = 0; j < 8; ++j) o[j] = f2bf((bf2f(cv[j]) - s[j] * di) * coef);
  ((u16x8*)nxt)[(size_t)v * 64 + lane] = o;
}

// ---------------- last diffusion step fused with h-sum ----------------
__global__ __launch_bounds__(256) void k_diffuse_final(const unsigned short* __restrict__ c0,
                                                       const unsigned short* __restrict__ c1,
                                                       const unsigned short* __restrict__ c2,
                                                       const unsigned short* __restrict__ cur,
                                                       unsigned short* __restrict__ hb,
                                                       const int* __restrict__ cnt_src,
                                                       const int* __restrict__ rp,
                                                       const int* __restrict__ col,
                                                       float coef, int n) {
  int w = threadIdx.x >> 6, lane = threadIdx.x & 63;
  int v = blockIdx.x * 4 + w;
  if (v >= n) return;
  int beg = rp[v], end = rp[v + 1];
  const u16x8* curv = (const u16x8*)cur;
  float s[8] = {0.f,0.f,0.f,0.f,0.f,0.f,0.f,0.f};
  #pragma unroll 4
  for (int e = beg; e < end; ++e) {
    int u = col[e];
    u16x8 r = curv[(size_t)u * 64 + lane];
    #pragma unroll
    for (int j = 0; j < 8; ++j) s[j] += bf2f(r[j]);
  }
  float di = 1.0f / (float)cnt_src[v];
  size_t o = (size_t)v * 64 + lane;
  u16x8 cv = curv[o];
  u16x8 a0 = ((const u16x8*)c0)[o];
  u16x8 a1 = ((const u16x8*)c1)[o];
  u16x8 a2 = ((const u16x8*)c2)[o];
  u16x8 hv;
  #pragma unroll
  for (int j = 0; j < 8; ++j) {
    float c3v = bf2f(cv[j]);
    float c4v = (c3v - s[j] * di) * coef;
    hv[j] = f2bf(bf2f(a0[j]) + bf2f(a1[j]) + bf2f(a2[j]) + c3v + c4v);
  }
  ((u16x8*)hb)[o] = hv;
}

// ---------------- BN finalize + normalize: bf16 out_pre -> f32 d_out ----------------
__global__ __launch_bounds__(256) void k_norm(const unsigned short* __restrict__ outpre,
                                              float* __restrict__ out,
                                              const float* __restrict__ colsum,
                                              const float* __restrict__ colsq,
                                              const float* __restrict__ gamma,
                                              const float* __restrict__ beta,
                                              float invn, int n4) {
  __shared__ float ssc[CC], ssh[CC];
  int t = threadIdx.x;
  for (int c = t; c < CC; c += 256) {
    float mean = colsum[c] * invn;
    float var = colsq[c] * invn - mean * mean;
    float sc = gamma[c] * rsqrtf(var + 1e-5f);
    ssc[c] = sc;
    ssh[c] = beta[c] - mean * sc;
  }
  __syncthreads();
  int i = blockIdx.x * blockDim.x + t;
  if (i >= n4) return;
  int c4 = i & (CC / 4 - 1);
  u16x4 v = ((const u16x4*)outpre)[i];
  f32x4 sc = *(const f32x4*)&ssc[c4 * 4];
  f32x4 sh = *(const f32x4*)&ssh[c4 * 4];
  f32x4 o;
  o[0] = bf2f(v[0]) * sc[0] + sh[0];
  o[1] = bf2f(v[1]) * sc[1] + sh[1];
  o[2] = bf2f(v[2]) * sc[2] + sh[2];
  o[3] = bf2f(v[3]) * sc[3] + sh[3];
  ((f32x4*)out)[i] = o;
}

// ---------------- orchestration ----------------
extern "C" void kernel_launch(void* const* d_in, const int* in_sizes, int n_in,
                              void* d_out, int out_size, void* d_ws, size_t ws_size,
                              hipStream_t stream) {
  (void)n_in; (void)out_size; (void)ws_size;
  const float* x    = (const float*)d_in[0];
  const float* W1   = (const float*)d_in[1];
  const float* b1   = (const float*)d_in[2];
  const float* W2   = (const float*)d_in[3];
  const float* b2   = (const float*)d_in[4];
  const float* Wlin = (const float*)d_in[5];
  const float* blin = (const float*)d_in[6];
  const float* gamma = (const float*)d_in[7];
  const float* beta  = (const float*)d_in[8];
  const int*   ei    = (const int*)d_in[9];

  const int n   = in_sizes[0] / CC;          // 20000
  const int E   = in_sizes[9] / 2;           // 160000
  const int GNN = in_sizes[2];               // 512
  const int NBP = in_sizes[4];               // 128
  const int* src = ei;
  const int* dst = ei + E;
  const int mt64 = (n + BM - 1) / BM;        // 313
  const int mpad = 20096;                    // multiple of 64 and 128
  const size_t SB = (size_t)mpad * CC;       // elements per bf16 buffer

  char* ws = (char*)d_ws;
  size_t off = 0;
  auto alloc = [&](size_t bytes) -> void* {
    void* p = ws + off;
    off = (off + bytes + 255) & ~(size_t)255;
    return p;
  };
  int*   cnt_src = (int*)alloc((size_t)n * 4);
  int*   cnt_dst = (int*)alloc((size_t)n * 4);
  int*   fil     = (int*)alloc((size_t)n * 4);
  int*   rp      = (int*)alloc((size_t)(n + 1) * 4);
  int*   colx    = (int*)alloc((size_t)E * 4);
  float* colsum  = (float*)alloc(CC * 4);
  float* colsq   = (float*)alloc(CC * 4);
  unsigned short* W1t = (unsigned short*)alloc((size_t)GNN * CC * 2);
  unsigned short* W2t = (unsigned short*)alloc((size_t)NBP * GNN * 2);
  unsigned short* Wlt = (unsigned short*)alloc((size_t)CC * CC * 2);
  u16x2* cs = (u16x2*)alloc((size_t)mpad * BB_ * 4);       // bf16 (cos,sin)
  unsigned short* c0 = (unsigned short*)alloc(SB * 2);     // phase A: xb; later out_pre
  unsigned short* c1 = (unsigned short*)alloc(SB * 2);     // phase A: G
  unsigned short* c2 = (unsigned short*)alloc(SB * 2);
  unsigned short* c3 = (unsigned short*)alloc(SB * 2);
  unsigned short* hb = (unsigned short*)alloc(SB * 2);
  unsigned short* xb = c0;
  unsigned short* G  = c1;
  unsigned short* outpre = c0;               // bf16 out staging (c0 dead after diffuse_final)

  // zero accumulator scratch
  k_zero<<<(n + 255) / 256, 256, 0, stream>>>(cnt_src, cnt_dst, fil, colsum, colsq, n);

  // graph prep
  k_count<<<(E + 255) / 256, 256, 0, stream>>>(src, dst, cnt_src, cnt_dst, E);
  k_scan<<<1, 1024, 0, stream>>>(cnt_dst, rp, n);
  k_fill<<<(E + 255) / 256, 256, 0, stream>>>(src, dst, rp, fil, colx, E);

  // converts
  int total4 = mpad * (CC / 4);
  k_conv_bf16<<<(total4 + 255) / 256, 256, 0, stream>>>(x, xb, n, total4);
  k_transconv_all<<<dim3(16, 16, 3), dim3(32, 8), 0, stream>>>(W1, W2, Wlin, W1t, W2t, Wlt);

  // struct encoder: G = gelu(x@W1+b1); GEMM2 fused: cs=bf16(cos,sin)(G@W2+b2), c0=bf16(Rx)
  k_gemm<1><<<mt64 * (GNN / BN), 256, 0, stream>>>(xb, W1t, b1, (void*)G, nullptr, nullptr,
                                                   nullptr, nullptr, nullptr, CC, GNN, n, GNN / BN);
  k_gemm<2><<<mt64 * (NBP / BN), 256, 0, stream>>>(G, W2t, b2, (void*)cs, x, c0,
                                                   nullptr, nullptr, nullptr, GNN, NBP, n, NBP / BN);

  // diffusion: c0 -> c1 -> c2 -> c3; last step fused with h-sum -> hb
  k_diffuse<<<(n + 3) / 4, 256, 0, stream>>>(c0, c1, cnt_src, rp, colx, -1.0f, n);
  k_diffuse<<<(n + 3) / 4, 256, 0, stream>>>(c1, c2, cnt_src, rp, colx, -0.5f, n);
  k_diffuse<<<(n + 3) / 4, 256, 0, stream>>>(c2, c3, cnt_src, rp, colx, -(1.0f / 3.0f), n);
  k_diffuse_final<<<(n + 3) / 4, 256, 0, stream>>>(c0, c1, c2, c3, hb, cnt_src, rp, colx, -0.25f, n);

  // GEMM3 fused: out_pre(bf16) = x + R^T(hb@Wlin+blin) + BN column stats (out_pre = c0, dead)
  k_gemm<3><<<mt64 * (CC / BN), 256, 0, stream>>>(hb, Wlt, blin, (void*)outpre, x, nullptr,
                                                  cs, colsum, colsq, CC, CC, n, CC / BN);

  // BN finalize + normalize: bf16 out_pre -> f32 d_out
  int nb = n * BB_;
  k_norm<<<(nb + 255) / 256, 256, 0, stream>>>(outpre, (float*)d_out, colsum, colsq, gamma, beta,
                                               1.0f / (float)n, nb);
}